// Round 1
// baseline (5918.664 us; speedup 1.0000x reference)
//
#include <hip/hip_runtime.h>
#include <math.h>

// Problem constants (from reference)
static constexpr int S   = 771;   // NB_LABELS*MAX_DEPTH + EXTRA
static constexpr int Tn  = 128;
static constexpr int Bn  = 32;
static constexpr int BOSs = 0;
static constexpr int EOSs = 1;
// Padded dims: JP = threads per block (13 waves), KP = inner-dim pad (mult of 16)
static constexpr int JP = 832;
static constexpr int KP = 784;
static constexpr int NW = JP / 64;  // 13 waves

__device__ __forceinline__ float wave_max_f(float v) {
    #pragma unroll
    for (int off = 32; off > 0; off >>= 1) v = fmaxf(v, __shfl_down(v, off));
    return v;
}
__device__ __forceinline__ float wave_sum_f(float v) {
    #pragma unroll
    for (int off = 32; off > 0; off >>= 1) v += __shfl_down(v, off);
    return v;
}

// Kernel A: expTt[j][i] = exp(trans[i][j]), transposed + zero-padded to JP x KP.
// exp(-1e9) flushes to exactly 0 -> forbidden transitions drop out of the dot.
extern "C" __global__ void build_expT(const float* __restrict__ trans,
                                      float* __restrict__ expTt) {
    int idx = blockIdx.x * blockDim.x + threadIdx.x;
    if (idx >= JP * KP) return;
    int jj = idx / KP;
    int ii = idx - jj * KP;
    float v = 0.f;
    if (jj < S && ii < S) v = __expf(trans[ii * S + jj]);
    expTt[idx] = v;
}

// Kernel B: gold-path scores per batch (exact fp32 lookups; holds the -1e9 terms
// that dominate the output magnitude).
extern "C" __global__ __launch_bounds__(Tn)
void crf_scores(const float* __restrict__ em, const int* __restrict__ tags,
                const float* __restrict__ mask, const float* __restrict__ trans,
                float* __restrict__ scores) {
    const int b = blockIdx.x, t = threadIdx.x;
    const int lane = t & 63, wid = t >> 6;
    __shared__ float redv[2], redm[2];

    float mk = mask[b * Tn + t];
    float val = 0.f;
    if (t > 0) {
        int cur  = tags[b * Tn + t];
        int prev = tags[b * Tn + t - 1];
        val = (em[((size_t)b * Tn + t) * S + cur] + trans[prev * S + cur]) * mk;
    }
    float v  = wave_sum_f(val);
    float ms = wave_sum_f(mk);
    if (lane == 0) { redv[wid] = v; redm[wid] = ms; }
    __syncthreads();
    if (t == 0) {
        float tot  = redv[0] + redv[1];
        float msum = redm[0] + redm[1];
        int last  = (int)(msum + 0.5f) - 1;
        int first = tags[b * Tn];
        int lastt = tags[b * Tn + last];
        scores[b] = tot + trans[BOSs * S + first]
                        + em[((size_t)b * Tn) * S + first]
                        + trans[lastt * S + EOSs];
    }
}

// Kernel C: forward algorithm, one workgroup per batch. Thread j owns state j.
// Per step: block-max M of alpha -> p = exp(alpha-M) in LDS -> dot(p, E^T row j)
// via float4 loads -> alpha' = M + log(dot) + em. 127 sequential steps, only
// __syncthreads() between them (no grid sync needed: batches independent).
extern "C" __global__ __launch_bounds__(JP)
void crf_forward(const float* __restrict__ em, const float* __restrict__ mask,
                 const float* __restrict__ trans, const float* __restrict__ expTt,
                 const float* __restrict__ scores, float* __restrict__ out) {
    const int b = blockIdx.x;
    const int j = threadIdx.x;
    const int lane = j & 63, wid = j >> 6;

    __shared__ float red[16];
    __shared__ __align__(16) float p[KP];

    float areg;
    if (j < S) areg = trans[BOSs * S + j] + em[(size_t)(b * Tn) * S + j];
    else       areg = -INFINITY;

    const float* __restrict__ eTrow = expTt + (size_t)j * KP;

    for (int t = 1; t < Tn; ++t) {
        // ---- block max of alpha ----
        float m = wave_max_f(areg);
        if (lane == 0) red[wid] = m;
        __syncthreads();
        if (wid == 0) {
            float x = (lane < NW) ? red[lane] : -INFINITY;
            x = wave_max_f(x);
            if (lane == 0) red[0] = x;
        }
        __syncthreads();
        const float Mv = red[0];

        // ---- p = exp(alpha - M), padded slots exactly 0 ----
        if (j < KP) p[j] = (j < S) ? __expf(areg - Mv) : 0.f;
        __syncthreads();

        // ---- dot(p, expT^T[j]) : fp32 FMA-bound inner loop ----
        float a0 = 0.f, a1 = 0.f, a2 = 0.f, a3 = 0.f;
        #pragma unroll 4
        for (int i = 0; i < KP; i += 16) {
            const float4 e0 = *(const float4*)(eTrow + i);
            const float4 e1 = *(const float4*)(eTrow + i + 4);
            const float4 e2 = *(const float4*)(eTrow + i + 8);
            const float4 e3 = *(const float4*)(eTrow + i + 12);
            const float4 p0 = *(const float4*)(p + i);
            const float4 p1 = *(const float4*)(p + i + 4);
            const float4 p2 = *(const float4*)(p + i + 8);
            const float4 p3 = *(const float4*)(p + i + 12);
            a0 += e0.x * p0.x + e0.y * p0.y + e0.z * p0.z + e0.w * p0.w;
            a1 += e1.x * p1.x + e1.y * p1.y + e1.z * p1.z + e1.w * p1.w;
            a2 += e2.x * p2.x + e2.y * p2.y + e2.z * p2.z + e2.w * p2.w;
            a3 += e3.x * p3.x + e3.y * p3.y + e3.z * p3.z + e3.w * p3.w;
        }
        float acc = (a0 + a1) + (a2 + a3);

        const float mval = mask[b * Tn + t];
        const float emv  = (j < S) ? em[((size_t)b * Tn + t) * S + j] : 0.f;
        float na = Mv + __logf(acc) + emv;   // log(0) = -inf for dead states: OK
        areg = (mval > 0.f) ? na : areg;
        __syncthreads();   // protects p[] and red[] for next iteration
    }

    // ---- log_Z = logsumexp_j(alpha[j] + trans[j][EOS]) ----
    float fv = (j < S) ? (areg + trans[(size_t)j * S + EOSs]) : -INFINITY;
    float m = wave_max_f(fv);
    if (lane == 0) red[wid] = m;
    __syncthreads();
    if (wid == 0) {
        float x = (lane < NW) ? red[lane] : -INFINITY;
        x = wave_max_f(x);
        if (lane == 0) red[0] = x;
    }
    __syncthreads();
    const float Mz = red[0];
    float e = (j < S) ? __expf(fv - Mz) : 0.f;
    float ssum = wave_sum_f(e);
    __syncthreads();            // everyone has read Mz before red[] is reused
    if (lane == 0) red[wid] = ssum;
    __syncthreads();
    if (wid == 0) {
        float x = (lane < NW) ? red[lane] : 0.f;
        x = wave_sum_f(x);
        if (lane == 0) {
            float logz = Mz + __logf(x);
            atomicAdd(out, -(scores[b] - logz));
        }
    }
}

extern "C" void kernel_launch(void* const* d_in, const int* in_sizes, int n_in,
                              void* d_out, int out_size, void* d_ws, size_t ws_size,
                              hipStream_t stream) {
    const float* em    = (const float*)d_in[0];
    const int*   tags  = (const int*)d_in[1];   // int32 (JAX x64 disabled)
    const float* mask  = (const float*)d_in[2];
    const float* trans = (const float*)d_in[3];
    float* out = (float*)d_out;

    float* expTt  = (float*)d_ws;                       // JP*KP floats (~2.6 MB)
    float* scores = expTt + (size_t)JP * KP;            // Bn floats

    hipMemsetAsync(d_out, 0, sizeof(float), stream);    // out is 0xAA-poisoned

    build_expT<<<(JP * KP + 255) / 256, 256, 0, stream>>>(trans, expTt);
    crf_scores<<<Bn, Tn, 0, stream>>>(em, tags, mask, trans, scores);
    crf_forward<<<Bn, JP, 0, stream>>>(em, mask, trans, expTt, scores, out);
}

// Round 3
// 1217.999 us; speedup vs baseline: 4.8593x; 4.8593x over previous
//
#include <hip/hip_runtime.h>
#include <math.h>

typedef __attribute__((ext_vector_type(2))) _Float16 half2_t;
typedef unsigned long long u64;

static constexpr int S    = 771;   // NB_LABELS*MAX_DEPTH + EXTRA
static constexpr int Tn   = 128;
static constexpr int Bn   = 32;
static constexpr int BOSs = 0;
static constexpr int EOSs = 1;

static constexpr int JPAD  = 832;            // 13 * 64 output-state pad
static constexpr int KPAD  = 800;            // 4 * 200 source-state pad
static constexpr int JB    = 13;             // blocks per batch
static constexpr int ROWS  = 64;             // output rows per block (= lanes)
static constexpr int NCH   = 4;              // K-chunks (= waves per block)
static constexpr int CHUNK = KPAD / NCH;     // 200 f16 per thread fragment
static constexpr int NH2   = CHUNK / 2;      // 100 half2 regs per thread
static constexpr int EBLK  = NCH * (CHUNK / 8) * ROWS * 8;  // 51200 f16 per jblk

__device__ __forceinline__ float dot2f(half2_t a, half2_t b, float c) {
    return __builtin_amdgcn_fdot2(a, b, c, false);   // compiled OK on gfx950 (r2 build passed)
}

__device__ __forceinline__ float wave_max_f(float v) {
    #pragma unroll
    for (int off = 32; off > 0; off >>= 1) v = fmaxf(v, __shfl_down(v, off));
    return v;
}
__device__ __forceinline__ float wave_sum_f(float v) {
    #pragma unroll
    for (int off = 32; off > 0; off >>= 1) v += __shfl_down(v, off);
    return v;
}

union F4H { float4 f; half2_t h[4]; };
union U64F2 { u64 q; float f[2]; };

__device__ __forceinline__ void ast(float* p, float v) {
    __hip_atomic_store(p, v, __ATOMIC_RELAXED, __HIP_MEMORY_SCOPE_AGENT);
}
__device__ __forceinline__ float ald(const float* p) {
    return __hip_atomic_load(p, __ATOMIC_RELAXED, __HIP_MEMORY_SCOPE_AGENT);
}
__device__ __forceinline__ void ald2(const float* p, float& a, float& b) {
    U64F2 u; u.q = __hip_atomic_load((const u64*)p, __ATOMIC_RELAXED,
                                     __HIP_MEMORY_SCOPE_AGENT);
    a = u.f[0]; b = u.f[1];
}

// ---------------------------------------------------------------------------
// Prep: swizzled f16 exp-transition table + trans[:,EOS] column.
// eswz[...] = exp(trans[i][j]), i = w*200 + kk*8 + e, j = jblk*64 + lane,
// laid out [jblk][w][kk][lane][8] so the fwd kernel's fragment load is
// lane-contiguous 16B. exp(-1e9) -> 0 exactly: forbidden transitions vanish.
// ---------------------------------------------------------------------------
extern "C" __global__ void build_tabs(const float* __restrict__ trans,
                                      _Float16* __restrict__ eswz,
                                      float* __restrict__ teos) {
    int idx = blockIdx.x * blockDim.x + threadIdx.x;
    if (idx < JPAD)
        teos[idx] = (idx < S) ? trans[idx * S + EOSs] : 0.f;
    if (idx >= JPAD * KPAD) return;
    int jblk = idx / EBLK;
    int r = idx - jblk * EBLK;
    int w = r / (EBLK / NCH);        r -= w * (EBLK / NCH);
    int kk = r / (ROWS * 8);         r -= kk * (ROWS * 8);
    int l = r / 8;
    int e = r - l * 8;
    int j = jblk * ROWS + l;
    int i = w * CHUNK + kk * 8 + e;
    float v = 0.f;
    if (i < S && j < S) v = __expf(trans[i * S + j]);
    eswz[idx] = (_Float16)v;
}

// ---------------------------------------------------------------------------
// Gold-path scores (unchanged from the passing round-1 kernel).
// ---------------------------------------------------------------------------
extern "C" __global__ __launch_bounds__(Tn)
void crf_scores(const float* __restrict__ em, const int* __restrict__ tags,
                const float* __restrict__ mask, const float* __restrict__ trans,
                float* __restrict__ scores) {
    const int b = blockIdx.x, t = threadIdx.x;
    const int lane = t & 63, wid = t >> 6;
    __shared__ float redv[2], redm[2];

    float mk = mask[b * Tn + t];
    float val = 0.f;
    if (t > 0) {
        int cur  = tags[b * Tn + t];
        int prev = tags[b * Tn + t - 1];
        val = (em[((size_t)b * Tn + t) * S + cur] + trans[prev * S + cur]) * mk;
    }
    float v  = wave_sum_f(val);
    float ms = wave_sum_f(mk);
    if (lane == 0) { redv[wid] = v; redm[wid] = ms; }
    __syncthreads();
    if (t == 0) {
        float tot  = redv[0] + redv[1];
        float msum = redm[0] + redm[1];
        int last  = (int)(msum + 0.5f) - 1;
        int first = tags[b * Tn];
        int lastt = tags[b * Tn + last];
        scores[b] = tot + trans[BOSs * S + first]
                        + em[((size_t)b * Tn) * S + first]
                        + trans[lastt * S + EOSs];
    }
}

// ---------------------------------------------------------------------------
// Forward algorithm: 13 blocks/batch (REGULAR launch, 416 blocks <= 512
// resident slots at __launch_bounds__(256,2) -> all co-resident, spin safe).
// Register-resident E f16 fragments; cross-block alpha + counter exchanged
// exclusively through agent-scope atomics (cross-XCD coherence point).
// Thread (w, lane): output row j = jblk*64+lane, K-chunk w (200 f16 in regs).
// ---------------------------------------------------------------------------
extern "C" __global__ __launch_bounds__(256, 2)
void crf_fwd(const float* __restrict__ em, const float* __restrict__ mask,
             const float* __restrict__ trans, const _Float16* __restrict__ eswz,
             const float* __restrict__ teos, const float* __restrict__ scores,
             float* __restrict__ abuf, unsigned* __restrict__ cnt,
             float* __restrict__ out) {
    const int jblk = blockIdx.x, b = blockIdx.y;
    const int tid = threadIdx.x, lane = tid & 63, w = tid >> 6;
    const int j0 = jblk * ROWS;

    __shared__ half2_t p2[KPAD / 2];   // exp(alpha - M) in f16
    __shared__ float part[256];        // per-(chunk,row) partial dots
    __shared__ float redm[NCH];
    __shared__ float reds[NCH];

    unsigned* mycnt = cnt + b * 32;    // 128B-strided counter per batch

    // ---- one-time: E^T fragment into 100 VGPRs (coalesced 16B loads) ----
    half2_t Ereg[NH2];
    {
        const _Float16* ep = eswz + (size_t)jblk * EBLK + ((w * 25) * 64 + lane) * 8;
        #pragma unroll
        for (int kk = 0; kk < 25; ++kk) {
            F4H u; u.f = *(const float4*)(ep + kk * 512);
            Ereg[kk * 4 + 0] = u.h[0];
            Ereg[kk * 4 + 1] = u.h[1];
            Ereg[kk * 4 + 2] = u.h[2];
            Ereg[kk * 4 + 3] = u.h[3];
        }
    }

    // ---- alpha0 = trans[BOS,:] + em[:,0,:] (wave 0 -> agent atomic store) ----
    if (w == 0) {
        int j = j0 + lane;
        float v = -INFINITY;
        if (j < S) v = trans[BOSs * S + j] + em[((size_t)b * Tn + 0) * S + j];
        ast(&abuf[(0 * Bn + b) * JPAD + j], v);
    }
    if (tid == 0)   // release-RMW: s_waitcnt drains wave-0's alpha stores first
        __hip_atomic_fetch_add(mycnt, 1u, __ATOMIC_RELEASE, __HIP_MEMORY_SCOPE_AGENT);

    // ---- 127 sequential steps ----
    for (int t = 1; t < Tn; ++t) {
        const float* abR = abuf + (((t - 1) & 1) * Bn + b) * JPAD;
        float*       abW = abuf + (((t    ) & 1) * Bn + b) * JPAD;

        if (tid == 0) {
            const unsigned tgt = (unsigned)(JB * t);
            while (__hip_atomic_load(mycnt, __ATOMIC_RELAXED,
                                     __HIP_MEMORY_SCOPE_AGENT) < tgt) {}
            (void)__hip_atomic_load(mycnt, __ATOMIC_ACQUIRE,
                                    __HIP_MEMORY_SCOPE_AGENT);
        }
        __syncthreads();

        // full alpha read (agent atomics, 2x 8B per thread) + early epilogue loads
        float a0 = -INFINITY, a1 = -INFINITY, a2 = -INFINITY, a3 = -INFINITY;
        if (tid < JPAD / 4) {
            ald2(abR + tid * 4,     a0, a1);
            ald2(abR + tid * 4 + 2, a2, a3);
        }
        float emv = 0.f, mval = 0.f, aold = 0.f;
        if (w == 0) {   // issued early: latency overlaps reductions + dot
            const int j = j0 + lane;
            aold = ald(&abR[j]);
            if (j < S) emv = em[((size_t)b * Tn + t) * S + j];
            mval = mask[b * Tn + t];
        }

        // block max of alpha
        float m = fmaxf(fmaxf(a0, a1), fmaxf(a2, a3));
        m = wave_max_f(m);
        if (lane == 0) redm[w] = m;
        __syncthreads();
        const float M = fmaxf(fmaxf(redm[0], redm[1]), fmaxf(redm[2], redm[3]));

        // p = exp(alpha - M) -> LDS f16 (pad/dead states -inf -> exactly 0)
        if (tid < KPAD / 4) {
            half2_t h01, h23;
            h01.x = (_Float16)__expf(a0 - M);
            h01.y = (_Float16)__expf(a1 - M);
            h23.x = (_Float16)__expf(a2 - M);
            h23.y = (_Float16)__expf(a3 - M);
            p2[tid * 2]     = h01;
            p2[tid * 2 + 1] = h23;
        }
        __syncthreads();

        // dot: register E x LDS p (all lanes same addr -> conflict-free bcast)
        float acc = 0.f;
        const half2_t* pw = p2 + w * NH2;
        #pragma unroll
        for (int kk = 0; kk < 25; ++kk) {
            F4H u; u.f = *(const float4*)(pw + kk * 4);
            acc = dot2f(Ereg[kk * 4 + 0], u.h[0], acc);
            acc = dot2f(Ereg[kk * 4 + 1], u.h[1], acc);
            acc = dot2f(Ereg[kk * 4 + 2], u.h[2], acc);
            acc = dot2f(Ereg[kk * 4 + 3], u.h[3], acc);
        }
        part[w * ROWS + lane] = acc;
        __syncthreads();

        // epilogue (wave 0): combine partials, log, mask-select, atomic store
        if (w == 0) {
            float s = part[lane] + part[ROWS + lane]
                    + part[2 * ROWS + lane] + part[3 * ROWS + lane];
            float nv = M + __logf(s) + emv;   // log(0)=-inf for dead states: OK
            ast(&abW[j0 + lane], (mval > 0.f) ? nv : aold);
        }
        if (tid == 0)
            __hip_atomic_fetch_add(mycnt, 1u, __ATOMIC_RELEASE,
                                   __HIP_MEMORY_SCOPE_AGENT);
        // next iteration's top __syncthreads protects p2/part/redm reuse
    }

    // ---- log_Z (block jblk==0 of each batch) ----
    if (jblk == 0) {
        if (tid == 0) {
            const unsigned tgt = (unsigned)(JB * Tn);
            while (__hip_atomic_load(mycnt, __ATOMIC_RELAXED,
                                     __HIP_MEMORY_SCOPE_AGENT) < tgt) {}
            (void)__hip_atomic_load(mycnt, __ATOMIC_ACQUIRE,
                                    __HIP_MEMORY_SCOPE_AGENT);
        }
        __syncthreads();
        const float* af = abuf + (((Tn - 1) & 1) * Bn + b) * JPAD;
        float f0 = -INFINITY, f1 = -INFINITY, f2 = -INFINITY, f3 = -INFINITY;
        if (tid < JPAD / 4) {
            float x0, x1, x2, x3;
            ald2(af + tid * 4,     x0, x1);
            ald2(af + tid * 4 + 2, x2, x3);
            const float4 tv = *(const float4*)(teos + tid * 4);
            f0 = x0 + tv.x; f1 = x1 + tv.y; f2 = x2 + tv.z; f3 = x3 + tv.w;
        }
        float m = fmaxf(fmaxf(f0, f1), fmaxf(f2, f3));
        m = wave_max_f(m);
        if (lane == 0) redm[w] = m;
        __syncthreads();
        const float M = fmaxf(fmaxf(redm[0], redm[1]), fmaxf(redm[2], redm[3]));
        float s = __expf(f0 - M) + __expf(f1 - M) + __expf(f2 - M) + __expf(f3 - M);
        s = wave_sum_f(s);
        if (lane == 0) reds[w] = s;
        __syncthreads();
        if (tid == 0) {
            float tot = reds[0] + reds[1] + reds[2] + reds[3];
            float logz = M + __logf(tot);
            atomicAdd(out, -(scores[b] - logz));
        }
    }
}

extern "C" void kernel_launch(void* const* d_in, const int* in_sizes, int n_in,
                              void* d_out, int out_size, void* d_ws, size_t ws_size,
                              hipStream_t stream) {
    const float* em    = (const float*)d_in[0];
    const int*   tags  = (const int*)d_in[1];
    const float* mask  = (const float*)d_in[2];
    const float* trans = (const float*)d_in[3];
    float* out = (float*)d_out;

    char* ws = (char*)d_ws;
    size_t off = 0;
    _Float16* eswz = (_Float16*)(ws + off);
    off += (size_t)JPAD * KPAD * sizeof(_Float16);
    off = (off + 255) & ~(size_t)255;
    float* teos = (float*)(ws + off);  off += JPAD * sizeof(float);
    off = (off + 255) & ~(size_t)255;
    float* abuf = (float*)(ws + off);  off += (size_t)2 * Bn * JPAD * sizeof(float);
    off = (off + 255) & ~(size_t)255;
    float* scores = (float*)(ws + off); off += Bn * sizeof(float);
    off = (off + 255) & ~(size_t)255;
    unsigned* cnt = (unsigned*)(ws + off); off += Bn * 32 * sizeof(unsigned);

    hipMemsetAsync(out, 0, sizeof(float), stream);
    hipMemsetAsync(cnt, 0, Bn * 32 * sizeof(unsigned), stream);

    build_tabs<<<(JPAD * KPAD + 255) / 256, 256, 0, stream>>>(trans, eswz, teos);
    crf_scores<<<Bn, Tn, 0, stream>>>(em, tags, mask, trans, scores);
    crf_fwd<<<dim3(JB, Bn), 256, 0, stream>>>(em, mask, trans, eswz, teos,
                                              scores, abuf, cnt, out);
}

// Round 4
// 451.879 us; speedup vs baseline: 13.0979x; 2.6954x over previous
//
#include <hip/hip_runtime.h>
#include <math.h>

typedef __attribute__((ext_vector_type(2))) _Float16 half2_t;
typedef unsigned long long u64;

static constexpr int S    = 771;   // NB_LABELS*MAX_DEPTH + EXTRA
static constexpr int Tn   = 128;
static constexpr int Bn   = 32;
static constexpr int BOSs = 0;
static constexpr int EOSs = 1;

static constexpr int JPAD  = 832;            // 13 * 64 output-state pad
static constexpr int KPAD  = 800;            // 4 * 200 source-state pad
static constexpr int JB    = 13;             // blocks per batch
static constexpr int ROWS  = 64;             // output rows per block (= lanes)
static constexpr int NCH   = 4;              // K-chunks (= waves per block)
static constexpr int CHUNK = KPAD / NCH;     // 200 f16 per thread fragment
static constexpr int NH2   = CHUNK / 2;      // 100 half2 regs per thread
static constexpr int EBLK  = NCH * (CHUNK / 8) * ROWS * 8;  // 51200 f16 per jblk
static constexpr int NLD   = JPAD / 4;       // 208 loader threads (4 u64 each)
static constexpr int NP2   = KPAD / 4;       // 200 exp-writer threads

__device__ __forceinline__ float dot2f(half2_t a, half2_t b, float c) {
    return __builtin_amdgcn_fdot2(a, b, c, false);
}
__device__ __forceinline__ float wave_max_f(float v) {
    #pragma unroll
    for (int off = 32; off > 0; off >>= 1) v = fmaxf(v, __shfl_down(v, off));
    return v;
}
__device__ __forceinline__ float wave_sum_f(float v) {
    #pragma unroll
    for (int off = 32; off > 0; off >>= 1) v += __shfl_down(v, off);
    return v;
}

union F4H { float4 f; half2_t h[4]; };

// tagged-alpha atomics: payload travels inside the atomic -> no fences needed
__device__ __forceinline__ u64 ald64(const u64* p) {
    return __hip_atomic_load((u64*)p, __ATOMIC_RELAXED, __HIP_MEMORY_SCOPE_AGENT);
}
__device__ __forceinline__ void ast64(u64* p, u64 v) {
    __hip_atomic_store(p, v, __ATOMIC_RELAXED, __HIP_MEMORY_SCOPE_AGENT);
}
__device__ __forceinline__ u64 pack(unsigned tag, float f) {
    return ((u64)tag << 32) | (u64)__float_as_uint(f);
}

// ---------------------------------------------------------------------------
// Prep: swizzled f16 exp-transition table + trans[:,EOS] column.
// eswz[...] = exp(trans[i][j]), i = w*200 + kk*8 + e, j = jblk*64 + lane,
// laid out [jblk][w][kk][lane][8] -> fwd kernel's fragment load is
// lane-contiguous 16B. exp(-1e9) -> 0 exactly: forbidden transitions vanish.
// ---------------------------------------------------------------------------
extern "C" __global__ void build_tabs(const float* __restrict__ trans,
                                      _Float16* __restrict__ eswz,
                                      float* __restrict__ teos) {
    int idx = blockIdx.x * blockDim.x + threadIdx.x;
    if (idx < JPAD)
        teos[idx] = (idx < S) ? trans[idx * S + EOSs] : 0.f;
    if (idx >= JPAD * KPAD) return;
    int jblk = idx / EBLK;
    int r = idx - jblk * EBLK;
    int w = r / (EBLK / NCH);        r -= w * (EBLK / NCH);
    int kk = r / (ROWS * 8);         r -= kk * (ROWS * 8);
    int l = r / 8;
    int e = r - l * 8;
    int j = jblk * ROWS + l;
    int i = w * CHUNK + kk * 8 + e;
    float v = 0.f;
    if (i < S && j < S) v = __expf(trans[i * S + j]);
    eswz[idx] = (_Float16)v;
}

// ---------------------------------------------------------------------------
// Gold-path scores (unchanged, passing since round 1).
// ---------------------------------------------------------------------------
extern "C" __global__ __launch_bounds__(Tn)
void crf_scores(const float* __restrict__ em, const int* __restrict__ tags,
                const float* __restrict__ mask, const float* __restrict__ trans,
                float* __restrict__ scores) {
    const int b = blockIdx.x, t = threadIdx.x;
    const int lane = t & 63, wid = t >> 6;
    __shared__ float redv[2], redm[2];

    float mk = mask[b * Tn + t];
    float val = 0.f;
    if (t > 0) {
        int cur  = tags[b * Tn + t];
        int prev = tags[b * Tn + t - 1];
        val = (em[((size_t)b * Tn + t) * S + cur] + trans[prev * S + cur]) * mk;
    }
    float v  = wave_sum_f(val);
    float ms = wave_sum_f(mk);
    if (lane == 0) { redv[wid] = v; redm[wid] = ms; }
    __syncthreads();
    if (t == 0) {
        float tot  = redv[0] + redv[1];
        float msum = redm[0] + redm[1];
        int last  = (int)(msum + 0.5f) - 1;
        int first = tags[b * Tn];
        int lastt = tags[b * Tn + last];
        scores[b] = tot + trans[BOSs * S + first]
                        + em[((size_t)b * Tn) * S + first]
                        + trans[lastt * S + EOSs];
    }
}

// ---------------------------------------------------------------------------
// Forward algorithm: 13 blocks/batch, 416 blocks co-resident at (256,2).
// Cross-block exchange: alpha packed as u64 {tag=t, f32} agent atomics.
// Consumers poll the DATA (tag match) -> sync + read in ONE L3 round trip,
// no counters, no fences, no serialized RMWs. Double-buffered by t&1;
// safety: a block writing t+1 has validated all of t, so transitively no
// block can still be reading the t-1 generation in that parity.
// ---------------------------------------------------------------------------
extern "C" __global__ __launch_bounds__(256, 2)
void crf_fwd(const float* __restrict__ em, const float* __restrict__ mask,
             const float* __restrict__ trans, const _Float16* __restrict__ eswz,
             const float* __restrict__ teos, const float* __restrict__ scores,
             u64* __restrict__ ab, float* __restrict__ out) {
    const int jblk = blockIdx.x, b = blockIdx.y;
    const int tid = threadIdx.x, lane = tid & 63, w = tid >> 6;
    const int j0 = jblk * ROWS;

    __shared__ half2_t p2[KPAD / 2];   // exp(alpha - M) in f16
    __shared__ float araw[JPAD];       // raw alpha (for wave0's aold)
    __shared__ float part[256];        // per-(chunk,row) partial dots
    __shared__ float redm[NCH];
    __shared__ float reds[NCH];

    // ---- one-time: E^T fragment into registers (coalesced 16B loads) ----
    half2_t Ereg[NH2];
    {
        const _Float16* ep = eswz + (size_t)jblk * EBLK + ((w * 25) * 64 + lane) * 8;
        #pragma unroll
        for (int kk = 0; kk < 25; ++kk) {
            F4H u; u.f = *(const float4*)(ep + kk * 512);
            Ereg[kk * 4 + 0] = u.h[0];
            Ereg[kk * 4 + 1] = u.h[1];
            Ereg[kk * 4 + 2] = u.h[2];
            Ereg[kk * 4 + 3] = u.h[3];
        }
    }

    // ---- alpha0 = trans[BOS,:] + em[:,0,:], tag 0 (own 64 rows) ----
    if (w == 0) {
        int j = j0 + lane;
        float v = -INFINITY;
        if (j < S) v = trans[BOSs * S + j] + em[((size_t)b * Tn + 0) * S + j];
        ast64(&ab[(0 * Bn + b) * JPAD + j], pack(0u, v));
    }

    // ---- 127 sequential steps ----
    for (int t = 1; t < Tn; ++t) {
        const u64* abR = ab + (((t - 1) & 1) * Bn + b) * JPAD;
        u64*       abW = ab + (((t    ) & 1) * Bn + b) * JPAD;

        // epilogue operands: independent of alpha -> issue before the poll,
        // their HBM latency hides inside the wait
        float emv = 0.f, mval = 0.f;
        if (w == 0) {
            const int j = j0 + lane;
            if (j < S) emv = em[((size_t)b * Tn + t) * S + j];
            mval = mask[b * Tn + t];
        }

        // ---- poll tagged alpha: sync == data arrival ----
        const unsigned tg = (unsigned)(t - 1);
        const u64* mp = abR + tid * 4;
        u64 q0 = 0, q1 = 0, q2 = 0, q3 = 0;
        bool ok = (tid >= NLD);
        while (true) {
            if (!ok) {
                q0 = ald64(mp);     q1 = ald64(mp + 1);
                q2 = ald64(mp + 2); q3 = ald64(mp + 3);
                ok = ((unsigned)(q0 >> 32) == tg) & ((unsigned)(q1 >> 32) == tg)
                   & ((unsigned)(q2 >> 32) == tg) & ((unsigned)(q3 >> 32) == tg);
            }
            if (__syncthreads_and(ok)) break;
        }
        float a0 = -INFINITY, a1 = -INFINITY, a2 = -INFINITY, a3 = -INFINITY;
        if (tid < NLD) {
            a0 = __uint_as_float((unsigned)q0);
            a1 = __uint_as_float((unsigned)q1);
            a2 = __uint_as_float((unsigned)q2);
            a3 = __uint_as_float((unsigned)q3);
            araw[tid * 4 + 0] = a0; araw[tid * 4 + 1] = a1;
            araw[tid * 4 + 2] = a2; araw[tid * 4 + 3] = a3;
        }

        // block max of alpha
        float m = fmaxf(fmaxf(a0, a1), fmaxf(a2, a3));
        m = wave_max_f(m);
        if (lane == 0) redm[w] = m;
        __syncthreads();
        const float M = fmaxf(fmaxf(redm[0], redm[1]), fmaxf(redm[2], redm[3]));

        // p = exp(alpha - M) -> LDS f16 (pad/dead states -inf -> exactly 0)
        if (tid < NP2) {
            half2_t h01, h23;
            h01.x = (_Float16)__expf(a0 - M);
            h01.y = (_Float16)__expf(a1 - M);
            h23.x = (_Float16)__expf(a2 - M);
            h23.y = (_Float16)__expf(a3 - M);
            p2[tid * 2]     = h01;
            p2[tid * 2 + 1] = h23;
        }
        __syncthreads();

        // dot: register E x LDS p (all lanes same addr -> conflict-free bcast)
        float acc = 0.f;
        const half2_t* pw = p2 + w * NH2;
        #pragma unroll
        for (int kk = 0; kk < 25; ++kk) {
            F4H u; u.f = *(const float4*)(pw + kk * 4);
            acc = dot2f(Ereg[kk * 4 + 0], u.h[0], acc);
            acc = dot2f(Ereg[kk * 4 + 1], u.h[1], acc);
            acc = dot2f(Ereg[kk * 4 + 2], u.h[2], acc);
            acc = dot2f(Ereg[kk * 4 + 3], u.h[3], acc);
        }
        part[w * ROWS + lane] = acc;
        __syncthreads();

        // epilogue (wave 0): combine partials, log, mask-select, tagged store
        if (w == 0) {
            float s = part[lane] + part[ROWS + lane]
                    + part[2 * ROWS + lane] + part[3 * ROWS + lane];
            float aold = araw[j0 + lane];
            float nv = M + __logf(s) + emv;   // log(0)=-inf for dead states: OK
            float res = (mval > 0.f) ? nv : aold;
            ast64(&abW[j0 + lane], pack((unsigned)t, res));
        }
        // next iteration's poll barrier protects all LDS reuse
    }

    // ---- log_Z (block jblk==0 of each batch) ----
    if (jblk == 0) {
        const u64* af = ab + (((Tn - 1) & 1) * Bn + b) * JPAD;
        const unsigned tg = (unsigned)(Tn - 1);
        const u64* mp = af + tid * 4;
        u64 q0 = 0, q1 = 0, q2 = 0, q3 = 0;
        bool ok = (tid >= NLD);
        while (true) {
            if (!ok) {
                q0 = ald64(mp);     q1 = ald64(mp + 1);
                q2 = ald64(mp + 2); q3 = ald64(mp + 3);
                ok = ((unsigned)(q0 >> 32) == tg) & ((unsigned)(q1 >> 32) == tg)
                   & ((unsigned)(q2 >> 32) == tg) & ((unsigned)(q3 >> 32) == tg);
            }
            if (__syncthreads_and(ok)) break;
        }
        float f0 = -INFINITY, f1 = -INFINITY, f2 = -INFINITY, f3 = -INFINITY;
        if (tid < NLD) {
            const float4 tv = *(const float4*)(teos + tid * 4);
            f0 = __uint_as_float((unsigned)q0) + tv.x;
            f1 = __uint_as_float((unsigned)q1) + tv.y;
            f2 = __uint_as_float((unsigned)q2) + tv.z;
            f3 = __uint_as_float((unsigned)q3) + tv.w;
        }
        float m = fmaxf(fmaxf(f0, f1), fmaxf(f2, f3));
        m = wave_max_f(m);
        if (lane == 0) redm[w] = m;
        __syncthreads();
        const float M = fmaxf(fmaxf(redm[0], redm[1]), fmaxf(redm[2], redm[3]));
        float s = __expf(f0 - M) + __expf(f1 - M) + __expf(f2 - M) + __expf(f3 - M);
        s = wave_sum_f(s);
        if (lane == 0) reds[w] = s;
        __syncthreads();
        if (tid == 0) {
            float tot = reds[0] + reds[1] + reds[2] + reds[3];
            float logz = M + __logf(tot);
            atomicAdd(out, -(scores[b] - logz));
        }
    }
}

extern "C" void kernel_launch(void* const* d_in, const int* in_sizes, int n_in,
                              void* d_out, int out_size, void* d_ws, size_t ws_size,
                              hipStream_t stream) {
    const float* em    = (const float*)d_in[0];
    const int*   tags  = (const int*)d_in[1];
    const float* mask  = (const float*)d_in[2];
    const float* trans = (const float*)d_in[3];
    float* out = (float*)d_out;

    char* ws = (char*)d_ws;
    size_t off = 0;
    _Float16* eswz = (_Float16*)(ws + off);
    off += (size_t)JPAD * KPAD * sizeof(_Float16);
    off = (off + 255) & ~(size_t)255;
    float* teos = (float*)(ws + off);  off += JPAD * sizeof(float);
    off = (off + 255) & ~(size_t)255;
    u64* ab = (u64*)(ws + off);        off += (size_t)2 * Bn * JPAD * sizeof(u64);
    off = (off + 255) & ~(size_t)255;
    float* scores = (float*)(ws + off); off += Bn * sizeof(float);

    // ws is re-poisoned 0xAA before every launch: stale tags never match t<128
    hipMemsetAsync(out, 0, sizeof(float), stream);

    build_tabs<<<(JPAD * KPAD + 255) / 256, 256, 0, stream>>>(trans, eswz, teos);
    crf_scores<<<Bn, Tn, 0, stream>>>(em, tags, mask, trans, scores);
    crf_fwd<<<dim3(JB, Bn), 256, 0, stream>>>(em, mask, trans, eswz, teos,
                                              scores, ab, out);
}

// Round 5
// 432.680 us; speedup vs baseline: 13.6791x; 1.0444x over previous
//
#include <hip/hip_runtime.h>
#include <math.h>

typedef __attribute__((ext_vector_type(2))) _Float16 half2_t;
typedef unsigned long long u64;

static constexpr int S    = 771;   // NB_LABELS*MAX_DEPTH + EXTRA
static constexpr int Tn   = 128;
static constexpr int Bn   = 32;
static constexpr int BOSs = 0;
static constexpr int EOSs = 1;

static constexpr int JPAD  = 832;            // 13 * 64 output-state pad
static constexpr int KPAD  = 800;            // 4 * 200 dot inner pad
static constexpr int JB    = 13;             // blocks per batch
static constexpr int ROWS  = 64;             // output rows per block (= lanes)
static constexpr int NCH   = 4;              // K-chunks (= waves per block)
static constexpr int CHUNK = KPAD / NCH;     // 200 f16 per thread fragment
static constexpr int NH2   = CHUNK / 2;      // 100 half2 regs per thread
static constexpr int EBLK  = NCH * (CHUNK / 8) * ROWS * 8;  // 51200 f16 per jblk
static constexpr int NG    = JB * 33;        // 429 u64 exchanged per (batch,step)
static constexpr int XSTR  = 432;            // padded stride (u64) per (parity,batch)
static constexpr float CBIAS = 6.0f;         // f16-overflow headroom in normalizer

__device__ __forceinline__ float dot2f(half2_t a, half2_t b, float c) {
    return __builtin_amdgcn_fdot2(a, b, c, false);
}
__device__ __forceinline__ float wave_max_bfly(float v) {   // result in ALL lanes
    #pragma unroll
    for (int off = 32; off > 0; off >>= 1) v = fmaxf(v, __shfl_xor(v, off));
    return v;
}
__device__ __forceinline__ float wave_sum_f(float v) {
    #pragma unroll
    for (int off = 32; off > 0; off >>= 1) v += __shfl_down(v, off);
    return v;
}

union F4H  { float4 f; half2_t h[4]; };
union U32H { unsigned u; half2_t h; };
union HU16 { _Float16 h; unsigned short u; };

__device__ __forceinline__ u64 ald64(const u64* p) {
    return __hip_atomic_load((u64*)p, __ATOMIC_RELAXED, __HIP_MEMORY_SCOPE_AGENT);
}
__device__ __forceinline__ void ast64(u64* p, u64 v) {
    __hip_atomic_store(p, v, __ATOMIC_RELAXED, __HIP_MEMORY_SCOPE_AGENT);
}
__device__ __forceinline__ u64 pack(unsigned tag, unsigned payload) {
    return ((u64)tag << 32) | (u64)payload;
}

// ---------------------------------------------------------------------------
// Prep: swizzled f16 exp-transition table + exp(trans[:,EOS]) column.
// eswz[...] = exp(trans[i][j]), i = w*200 + kk*8 + e, j = jblk*64 + lane,
// laid out [jblk][w][kk][lane][8] -> fwd fragment load is lane-contiguous 16B.
// exp(-1e9) -> 0 exactly: forbidden transitions vanish from the dots.
// ---------------------------------------------------------------------------
extern "C" __global__ void build_tabs(const float* __restrict__ trans,
                                      _Float16* __restrict__ eswz,
                                      float* __restrict__ eteos) {
    int idx = blockIdx.x * blockDim.x + threadIdx.x;
    if (idx < JPAD)
        eteos[idx] = (idx < S) ? __expf(trans[idx * S + EOSs]) : 0.f;
    if (idx >= JPAD * KPAD) return;
    int jblk = idx / EBLK;
    int r = idx - jblk * EBLK;
    int w = r / (EBLK / NCH);        r -= w * (EBLK / NCH);
    int kk = r / (ROWS * 8);         r -= kk * (ROWS * 8);
    int l = r / 8;
    int e = r - l * 8;
    int j = jblk * ROWS + l;
    int i = w * CHUNK + kk * 8 + e;
    float v = 0.f;
    if (i < S && j < S) v = __expf(trans[i * S + j]);
    eswz[idx] = (_Float16)v;
}

// ---------------------------------------------------------------------------
// Gold-path scores (unchanged, passing since round 1).
// ---------------------------------------------------------------------------
extern "C" __global__ __launch_bounds__(Tn)
void crf_scores(const float* __restrict__ em, const int* __restrict__ tags,
                const float* __restrict__ mask, const float* __restrict__ trans,
                float* __restrict__ scores) {
    const int b = blockIdx.x, t = threadIdx.x;
    const int lane = t & 63, wid = t >> 6;
    __shared__ float redv[2], redm[2];

    float mk = mask[b * Tn + t];
    float val = 0.f;
    if (t > 0) {
        int cur  = tags[b * Tn + t];
        int prev = tags[b * Tn + t - 1];
        val = (em[((size_t)b * Tn + t) * S + cur] + trans[prev * S + cur]) * mk;
    }
    float v  = wave_sum_f(val);
    float ms = wave_sum_f(mk);
    if (lane == 0) { redv[wid] = v; redm[wid] = ms; }
    __syncthreads();
    if (t == 0) {
        float tot  = redv[0] + redv[1];
        float msum = redm[0] + redm[1];
        int last  = (int)(msum + 0.5f) - 1;
        int first = tags[b * Tn];
        int lastt = tags[b * Tn + last];
        scores[b] = tot + trans[BOSs * S + first]
                        + em[((size_t)b * Tn) * S + first]
                        + trans[lastt * S + EOSs];
    }
}

// publish (wave 0 only): own 64 rows' alpha -> p=exp(alpha-C) f16 pairs + chunk
// max, as 33 tagged u64 agent atomics. Exchange stream carries its own sync.
__device__ __forceinline__ void publish(u64* W, int jblk, unsigned tag,
                                        float af, float C, int lane) {
    float xf = __expf(af - C);          // -inf -> 0 exactly
    HU16 cv; cv.h = (_Float16)xf;
    unsigned us = cv.u;
    unsigned aa = (unsigned)__shfl((int)us, 2 * lane);
    unsigned bb = (unsigned)__shfl((int)us, 2 * lane + 1);
    float mc = wave_max_bfly(af);
    u64* base = W + 33 * jblk;
    if (lane < 32)  ast64(base + lane, pack(tag, aa | (bb << 16)));
    if (lane == 32) ast64(base + 32,   pack(tag, __float_as_uint(mc)));
}

// ---------------------------------------------------------------------------
// Forward algorithm, producer-normalized exchange:
//   x_j(t) = exp(alpha_j(t) - C_t) in f16, C_t = Mb_{t-1} + 6, where Mb is the
//   max of the 13 per-chunk maxes riding in the same tagged stream. Every
//   block derives C_t identically from step t-1 data -> no extra sync hop.
// Consumer: poll 429 tagged u64 -> f16 pairs go STRAIGHT into LDS p2 (no exp,
// no max reduce on the critical path) -> dot vs register E -> epilogue:
// alpha' = C + log(dot) + em, publish. 3 __syncthreads per step.
// ---------------------------------------------------------------------------
extern "C" __global__ __launch_bounds__(256, 2)
void crf_fwd(const float* __restrict__ em, const float* __restrict__ mask,
             const float* __restrict__ trans, const _Float16* __restrict__ eswz,
             const float* __restrict__ eteos, const float* __restrict__ scores,
             u64* __restrict__ xb, float* __restrict__ out) {
    const int jblk = blockIdx.x, b = blockIdx.y;
    const int tid = threadIdx.x, lane = tid & 63, w = tid >> 6;
    const int j0 = jblk * ROWS;

    __shared__ __align__(16) half2_t p2[JPAD / 2];  // 416 half2 of exchanged p
    __shared__ float mch[16];          // 13 per-chunk maxes
    __shared__ float part[256];        // per-(chunk,row) partial dots
    __shared__ float reds[NCH];
    __shared__ float cshare;           // C of the final publish (for log_Z)

    // ---- one-time: E^T fragment into registers (coalesced 16B loads) ----
    half2_t Ereg[NH2];
    {
        const _Float16* ep = eswz + (size_t)jblk * EBLK + ((w * 25) * 64 + lane) * 8;
        #pragma unroll
        for (int kk = 0; kk < 25; ++kk) {
            F4H u; u.f = *(const float4*)(ep + kk * 512);
            Ereg[kk * 4 + 0] = u.h[0];
            Ereg[kk * 4 + 1] = u.h[1];
            Ereg[kk * 4 + 2] = u.h[2];
            Ereg[kk * 4 + 3] = u.h[3];
        }
    }

    // wave-0 per-lane state: alpha of own row, and the running normalizers
    float af = -INFINITY;
    float Cuse = CBIAS;                // C the producers of step-(t-1) x used

    if (w == 0) {
        int j = j0 + lane;
        if (j < S) af = trans[BOSs * S + j] + em[((size_t)b * Tn + 0) * S + j];
        publish(xb + ((size_t)0 * Bn + b) * XSTR, jblk, 0u, af, CBIAS, lane);
    }

    const int g0 = tid * 2, g1 = g0 + 1;
    const bool act0 = (g0 < NG), act1 = (g1 < NG);

    // ---- 127 sequential steps ----
    for (int t = 1; t < Tn; ++t) {
        const u64* R = xb + ((size_t)((t - 1) & 1) * Bn + b) * XSTR;
        u64*       W = xb + ((size_t)((t    ) & 1) * Bn + b) * XSTR;

        // epilogue operands independent of alpha: issue before the poll
        float emv = 0.f, mval = 0.f;
        if (w == 0) {
            const int j = j0 + lane;
            if (j < S) emv = em[((size_t)b * Tn + t) * S + j];
            mval = mask[b * Tn + t];
        }

        // ---- poll tagged stream: sync == data arrival ----
        const unsigned tg = (unsigned)(t - 1);
        u64 q0 = 0, q1 = 0;
        bool ok = !act0;
        while (true) {
            if (!ok) {
                q0 = ald64(R + g0);
                bool o0 = ((unsigned)(q0 >> 32) == tg);
                bool o1 = true;
                if (act1) { q1 = ald64(R + g1); o1 = ((unsigned)(q1 >> 32) == tg); }
                ok = o0 & o1;
            }
            if (__syncthreads_and(ok)) break;
        }

        // ---- unpack: f16 pairs straight into p2; chunk maxes into mch ----
        if (act0) {
            int c = g0 / 33, sl = g0 - c * 33;
            if (sl == 32) mch[c] = __uint_as_float((unsigned)q0);
            else { U32H v; v.u = (unsigned)q0; p2[c * 32 + sl] = v.h; }
        }
        if (act1) {
            int c = g1 / 33, sl = g1 - c * 33;
            if (sl == 32) mch[c] = __uint_as_float((unsigned)q1);
            else { U32H v; v.u = (unsigned)q1; p2[c * 32 + sl] = v.h; }
        }
        __syncthreads();

        // wave 0: next normalizer from this step's chunk maxes (off critical
        // path for other waves; ~50 cy)
        float Cnew = 0.f;
        if (w == 0) {
            float mv = (lane < 13) ? mch[lane] : -INFINITY;
            Cnew = wave_max_bfly(mv) + CBIAS;
        }

        // ---- dot: register E x LDS p (same-addr broadcast, conflict-free) ----
        float acc = 0.f;
        const half2_t* pw = p2 + w * NH2;
        #pragma unroll
        for (int kk = 0; kk < 25; ++kk) {
            F4H u; u.f = *(const float4*)(pw + kk * 4);
            acc = dot2f(Ereg[kk * 4 + 0], u.h[0], acc);
            acc = dot2f(Ereg[kk * 4 + 1], u.h[1], acc);
            acc = dot2f(Ereg[kk * 4 + 2], u.h[2], acc);
            acc = dot2f(Ereg[kk * 4 + 3], u.h[3], acc);
        }
        part[w * ROWS + lane] = acc;
        __syncthreads();

        // ---- epilogue (wave 0): alpha' = Cuse + log(dot) + em, publish ----
        if (w == 0) {
            float s4 = part[lane] + part[ROWS + lane]
                     + part[2 * ROWS + lane] + part[3 * ROWS + lane];
            float nv = Cuse + __logf(s4) + emv;   // log(0)=-inf for dead rows
            af = (mval > 0.f) ? nv : af;
            publish(W, jblk, (unsigned)t, af, Cnew, lane);
            if (lane == 0) cshare = Cnew;
            Cuse = Cnew;
        }
        // next poll's __syncthreads_and protects p2/mch/part reuse
    }

    // ---- log_Z (block jblk==0 of each batch): dot with exp(trans[:,EOS]) ----
    if (jblk == 0) {
        const u64* R = xb + ((size_t)((Tn - 1) & 1) * Bn + b) * XSTR;
        const unsigned tg = (unsigned)(Tn - 1);
        u64 q0 = 0, q1 = 0;
        bool ok = !act0;
        while (true) {
            if (!ok) {
                q0 = ald64(R + g0);
                bool o0 = ((unsigned)(q0 >> 32) == tg);
                bool o1 = true;
                if (act1) { q1 = ald64(R + g1); o1 = ((unsigned)(q1 >> 32) == tg); }
                ok = o0 & o1;
            }
            if (__syncthreads_and(ok)) break;
        }
        float lsum = 0.f;
        if (act0) {
            int c = g0 / 33, sl = g0 - c * 33;
            if (sl < 32) {
                U32H v; v.u = (unsigned)q0;
                int st = c * 64 + sl * 2;
                lsum += (float)v.h.x * eteos[st] + (float)v.h.y * eteos[st + 1];
            }
        }
        if (act1) {
            int c = g1 / 33, sl = g1 - c * 33;
            if (sl < 32) {
                U32H v; v.u = (unsigned)q1;
                int st = c * 64 + sl * 2;
                lsum += (float)v.h.x * eteos[st] + (float)v.h.y * eteos[st + 1];
            }
        }
        lsum = wave_sum_f(lsum);
        if (lane == 0) reds[w] = lsum;
        __syncthreads();
        if (tid == 0) {
            float tot = reds[0] + reds[1] + reds[2] + reds[3];
            float logz = cshare + __logf(tot);   // x already exp(alpha - C_127)
            atomicAdd(out, -(scores[b] - logz));
        }
    }
}

extern "C" void kernel_launch(void* const* d_in, const int* in_sizes, int n_in,
                              void* d_out, int out_size, void* d_ws, size_t ws_size,
                              hipStream_t stream) {
    const float* em    = (const float*)d_in[0];
    const int*   tags  = (const int*)d_in[1];
    const float* mask  = (const float*)d_in[2];
    const float* trans = (const float*)d_in[3];
    float* out = (float*)d_out;

    char* ws = (char*)d_ws;
    size_t off = 0;
    _Float16* eswz = (_Float16*)(ws + off);
    off += (size_t)JPAD * KPAD * sizeof(_Float16);
    off = (off + 255) & ~(size_t)255;
    float* eteos = (float*)(ws + off); off += JPAD * sizeof(float);
    off = (off + 255) & ~(size_t)255;
    u64* xb = (u64*)(ws + off);        off += (size_t)2 * Bn * XSTR * sizeof(u64);
    off = (off + 255) & ~(size_t)255;
    float* scores = (float*)(ws + off); off += Bn * sizeof(float);

    // ws re-poisoned 0xAA pre-launch: stale tags (0xAAAAAAAA) never match t<128
    hipMemsetAsync(out, 0, sizeof(float), stream);

    build_tabs<<<(JPAD * KPAD + 255) / 256, 256, 0, stream>>>(trans, eswz, eteos);
    crf_scores<<<Bn, Tn, 0, stream>>>(em, tags, mask, trans, scores);
    crf_fwd<<<dim3(JB, Bn), 256, 0, stream>>>(em, mask, trans, eswz, eteos,
                                              scores, xb, out);
}